// Round 2
// baseline (84.046 us; speedup 1.0000x reference)
//
#include <hip/hip_runtime.h>

// One wave (64 lanes) per ray. N=1024 voxels -> each lane owns 16 voxels
// (registers only). Sorted front-to-back composite via iterative wave-wide
// min-selection on key = (sortable_tn << 32) | voxel_idx, which reproduces
// jnp.argsort's stable tie-break (ties -> lower voxel index first).
// No LDS, no __syncthreads, no atomics.

#define CH 16            // chunks per lane = N / 64
#define EARLY_STOP 0.01f

__device__ __forceinline__ unsigned long long shfl_xor_u64(unsigned long long v, int m) {
    unsigned lo = (unsigned)v, hi = (unsigned)(v >> 32);
    lo = __shfl_xor(lo, m, 64);
    hi = __shfl_xor(hi, m, 64);
    return ((unsigned long long)hi << 32) | lo;
}

__global__ __launch_bounds__(256) void voxel_raster_wave(
    const float* __restrict__ positions, const float* __restrict__ sizes,
    const float* __restrict__ densities, const float* __restrict__ colors,
    const float* __restrict__ ray_o, const float* __restrict__ ray_d,
    float* __restrict__ out, int B)
{
    const int lane = threadIdx.x & 63;
    const int r    = blockIdx.x * 4 + (threadIdx.x >> 6);
    if (r >= B) return;

    const float ox = ray_o[r * 3 + 0], oy = ray_o[r * 3 + 1], oz = ray_o[r * 3 + 2];
    const float dx = ray_d[r * 3 + 0], dy = ray_d[r * 3 + 1], dz = ray_d[r * 3 + 2];
    const float ivx = 1.0f / dx, ivy = 1.0f / dy, ivz = 1.0f / dz;

    // degree-2 real SH basis at ray direction (wave-uniform)
    float sh[9];
    sh[0] = 1.0f;  sh[1] = dy;    sh[2] = dz;              sh[3] = dx;
    sh[4] = dx*dy; sh[5] = dy*dz; sh[6] = 3.0f*dz*dz-1.0f;
    sh[7] = dx*dz; sh[8] = dx*dx - dy*dy;

    // ---- phase 1: intersect my 16 voxels, keep tn + valid mask in regs ----
    float tnr[CH];
    unsigned vmask = 0;
    #pragma unroll
    for (int c = 0; c < CH; ++c) {
        const int n = c * 64 + lane;
        const float half = sizes[n] * 0.5f;
        const float px = positions[n * 3 + 0];
        const float py = positions[n * 3 + 1];
        const float pz = positions[n * 3 + 2];
        float a0 = (px - half - ox) * ivx, a1 = (px + half - ox) * ivx;
        float tn = fminf(a0, a1), tf = fmaxf(a0, a1);
        a0 = (py - half - oy) * ivy; a1 = (py + half - oy) * ivy;
        tn = fmaxf(tn, fminf(a0, a1)); tf = fminf(tf, fmaxf(a0, a1));
        a0 = (pz - half - oz) * ivz; a1 = (pz + half - oz) * ivz;
        tn = fmaxf(tn, fminf(a0, a1)); tf = fminf(tf, fmaxf(a0, a1));
        tnr[c] = tn;
        if ((tf > tn) && (tf > 0.0f)) vmask |= (1u << c);
    }

    const bool has_hit = __any(vmask != 0);

    // ---- phase 2: iterative min-selection + front-to-back composite ----
    float T = 1.0f, ra = 0.f, ga = 0.f, ba = 0.f, da = 0.f, wa = 0.f;
    for (;;) {
        // per-lane best key among remaining candidates
        unsigned long long best = ~0ull;
        #pragma unroll
        for (int c = 0; c < CH; ++c) {
            if (vmask & (1u << c)) {
                unsigned u = __float_as_uint(tnr[c]);
                u = (u & 0x80000000u) ? ~u : (u | 0x80000000u);
                const unsigned long long k =
                    ((unsigned long long)u << 32) | (unsigned)(c * 64 + lane);
                if (k < best) best = k;
            }
        }
        // wave-wide min (6 butterfly steps)
        #pragma unroll
        for (int off = 32; off > 0; off >>= 1) {
            const unsigned long long o = shfl_xor_u64(best, off);
            if (o < best) best = o;
        }
        if (best == ~0ull) break;       // no candidates left
        if (T < EARLY_STOP) break;      // proc = (T_before >= EARLY_STOP_T)

        const int n = (int)(best & 0xFFFFFFFFu);
        if (lane == (n & 63)) vmask &= ~(1u << (n >> 6));   // owner retires it

        // exact tn from the sort key (bit-inverse of the flip transform)
        unsigned u = (unsigned)(best >> 32);
        u = (u & 0x80000000u) ? (u ^ 0x80000000u) : ~u;
        const float tn = __uint_as_float(u);

        // recompute tf for the winning voxel (wave-uniform, L2-resident)
        const float half = sizes[n] * 0.5f;
        const float px = positions[n * 3 + 0];
        const float py = positions[n * 3 + 1];
        const float pz = positions[n * 3 + 2];
        float a0 = (px - half - ox) * ivx, a1 = (px + half - ox) * ivx;
        float tf = fmaxf(a0, a1);
        a0 = (py - half - oy) * ivy; a1 = (py + half - oy) * ivy;
        tf = fminf(tf, fmaxf(a0, a1));
        a0 = (pz - half - oz) * ivz; a1 = (pz + half - oz) * ivz;
        tf = fminf(tf, fmaxf(a0, a1));

        // within-voxel alpha compositing (S=8, constant sigma)
        const float sigma = expf(densities[n]);
        const float dt    = tf - tn;
        const float alpha = 1.0f - expf(-sigma * dt * 0.125f);
        const float base  = 1.0f - alpha + 1e-8f;
        float pw = 1.0f, ws = 0.0f, dep = 0.0f;
        #pragma unroll
        for (int i = 0; i < 8; i++) {
            const float w  = alpha * pw;
            const float ts = tn + dt * ((float)i * (1.0f / 7.0f));
            ws  += w;
            dep += w * ts;
            pw  *= base;
        }

        // SH color + sigmoid (3 channels, 9 coeffs)
        float rgb[3];
        #pragma unroll
        for (int k = 0; k < 3; k++) {
            float acc = 0.0f;
            #pragma unroll
            for (int c = 0; c < 9; c++)
                acc += sh[c] * colors[n * 27 + k * 9 + c];
            rgb[k] = 1.0f / (1.0f + expf(-acc));
        }

        const float cw = T * ws;
        ra += cw * rgb[0];
        ga += cw * rgb[1];
        ba += cw * rgb[2];
        da += T * dep;
        wa += cw;
        T  *= (1.0f - ws);
    }

    if (lane == 0) {
        out[r * 3 + 0] = ra;
        out[r * 3 + 1] = ga;
        out[r * 3 + 2] = ba;
        out[B * 3 + r] = has_hit ? da : 100.0f;   // FAR_PLANE when no hit
        out[B * 4 + r] = wa;
    }
}

extern "C" void kernel_launch(void* const* d_in, const int* in_sizes, int n_in,
                              void* d_out, int out_size, void* d_ws, size_t ws_size,
                              hipStream_t stream) {
    const float* positions = (const float*)d_in[0];
    const float* sizes     = (const float*)d_in[1];
    const float* densities = (const float*)d_in[2];
    const float* colors    = (const float*)d_in[3];
    const float* ray_o     = (const float*)d_in[4];
    const float* ray_d     = (const float*)d_in[5];
    const int B = in_sizes[4] / 3;      // 2048 rays (N fixed at 1024 = CH*64)

    voxel_raster_wave<<<(B + 3) / 4, 256, 0, stream>>>(
        positions, sizes, densities, colors, ray_o, ray_d, (float*)d_out, B);
}

// Round 3
// 73.116 us; speedup vs baseline: 1.1495x; 1.1495x over previous
//
#include <hip/hip_runtime.h>

// Block-per-ray (2048 blocks x 256 threads = 8 blocks/CU, single wave of
// dispatch). Phase 1: 4 voxels/thread AABB intersect + payload (ws, depth,
// SH rgb) computed at detection, compacted into LDS via shared atomic.
// Phase 2 (wave 0 only): rank-by-counting on key=(sortable_tn<<32)|voxel_idx
// (exact jnp.argsort stable semantics), scatter to sorted arrays.
// Phase 3 (wave 0): wave-parallel composite — exclusive prefix product of
// (1-ws) via shfl_up scan gives T_before; proc = (T_before >= 0.01) is the
// reference's exact early-stop mask; masked sums + butterfly reduce.
// 2 barriers after init, ~6.7 KB LDS, no bitonic sort, no serial tail.

#define BLOCK 256
#define VPT   4          // voxels per thread (N = 1024)
#define CAP   128        // max stored hits (expected ~5 per ray)
#define EARLY_STOP 0.01f

__global__ __launch_bounds__(BLOCK) void voxel_raster(
    const float* __restrict__ positions, const float* __restrict__ sizes,
    const float* __restrict__ densities, const float* __restrict__ colors,
    const float* __restrict__ ray_o, const float* __restrict__ ray_d,
    float* __restrict__ out, int N, int B)
{
    const int b   = blockIdx.x;
    const int tid = threadIdx.x;

    __shared__ int cnt;
    __shared__ unsigned long long key[CAP];
    __shared__ float raw_ws[CAP], raw_dep[CAP], raw_r[CAP], raw_g[CAP], raw_b[CAP];
    __shared__ float s_ws[CAP],  s_dep[CAP],  s_r[CAP],  s_g[CAP],  s_b[CAP];

    if (tid == 0) cnt = 0;
    __syncthreads();

    const float ox = ray_o[b*3+0], oy = ray_o[b*3+1], oz = ray_o[b*3+2];
    const float dx = ray_d[b*3+0], dy = ray_d[b*3+1], dz = ray_d[b*3+2];
    const float ivx = 1.0f/dx, ivy = 1.0f/dy, ivz = 1.0f/dz;

    // degree-2 real SH basis at ray direction (block-uniform)
    float sh[9];
    sh[0]=1.0f; sh[1]=dy; sh[2]=dz; sh[3]=dx;
    sh[4]=dx*dy; sh[5]=dy*dz; sh[6]=3.0f*dz*dz-1.0f; sh[7]=dx*dz; sh[8]=dx*dx-dy*dy;

    // ---- phase 1: intersect + payload + compact ----
    #pragma unroll
    for (int k = 0; k < VPT; ++k) {
        const int n = tid + k * BLOCK;
        const float half = sizes[n] * 0.5f;
        const float px = positions[n*3+0];
        const float py = positions[n*3+1];
        const float pz = positions[n*3+2];

        float a0 = (px - half - ox) * ivx, a1 = (px + half - ox) * ivx;
        float tn = fminf(a0, a1), tf = fmaxf(a0, a1);
        a0 = (py - half - oy) * ivy; a1 = (py + half - oy) * ivy;
        tn = fmaxf(tn, fminf(a0, a1)); tf = fminf(tf, fmaxf(a0, a1));
        a0 = (pz - half - oz) * ivz; a1 = (pz + half - oz) * ivz;
        tn = fmaxf(tn, fminf(a0, a1)); tf = fminf(tf, fmaxf(a0, a1));

        if ((tf > tn) && (tf > 0.0f)) {
            // within-voxel alpha compositing (S=8, constant sigma)
            const float sigma = expf(densities[n]);
            const float dt    = tf - tn;
            const float alpha = 1.0f - expf(-sigma * dt * 0.125f);
            const float base  = 1.0f - alpha + 1e-8f;
            float pw = 1.0f, ws = 0.0f, dep = 0.0f;
            #pragma unroll
            for (int i = 0; i < 8; i++) {
                const float w  = alpha * pw;
                const float ts = tn + dt * ((float)i * (1.0f / 7.0f));
                ws  += w;
                dep += w * ts;
                pw  *= base;
            }
            // SH color + sigmoid
            float rgb[3];
            #pragma unroll
            for (int c3 = 0; c3 < 3; c3++) {
                float acc = 0.0f;
                #pragma unroll
                for (int c = 0; c < 9; c++)
                    acc += sh[c] * colors[n*27 + c3*9 + c];
                rgb[c3] = 1.0f / (1.0f + expf(-acc));
            }

            const int slot = atomicAdd(&cnt, 1);
            if (slot < CAP) {
                unsigned u = __float_as_uint(tn);
                u = (u & 0x80000000u) ? ~u : (u | 0x80000000u);
                key[slot]     = ((unsigned long long)u << 32) | (unsigned)n;
                raw_ws[slot]  = ws;
                raw_dep[slot] = dep;
                raw_r[slot]   = rgb[0];
                raw_g[slot]   = rgb[1];
                raw_b[slot]   = rgb[2];
            }
        }
    }
    __syncthreads();

    const int total = cnt;
    const int m = (total < CAP) ? total : CAP;

    // ---- phase 2 (wave 0): rank-by-counting + scatter to sorted order ----
    if (tid < 64) {
        for (int l = tid; l < m; l += 64) {
            const unsigned long long kl = key[l];
            int rank = 0;
            for (int j = 0; j < m; ++j) rank += (key[j] < kl);
            s_ws[rank]  = raw_ws[l];
            s_dep[rank] = raw_dep[l];
            s_r[rank]   = raw_r[l];
            s_g[rank]   = raw_g[l];
            s_b[rank]   = raw_b[l];
        }
    }
    __syncthreads();

    // ---- phase 3 (wave 0): wave-parallel sorted composite ----
    if (tid < 64) {
        const int lane = tid;
        float ra = 0.f, ga = 0.f, ba = 0.f, da = 0.f, wa = 0.f;
        float Tc = 1.0f;                        // carry across 64-wide chunks
        for (int basei = 0; basei < m; basei += 64) {
            const int idx = basei + lane;
            float ws = 0.f, dep = 0.f, cr = 0.f, cg = 0.f, cb = 0.f;
            if (idx < m) {
                ws = s_ws[idx]; dep = s_dep[idx];
                cr = s_r[idx];  cg = s_g[idx];  cb = s_b[idx];
            }
            // inclusive prefix product of (1-ws) across the wave
            float p = 1.0f - ws;
            #pragma unroll
            for (int off = 1; off < 64; off <<= 1) {
                const float q = __shfl_up(p, off, 64);
                if (lane >= off) p *= q;
            }
            float excl = __shfl_up(p, 1, 64);
            if (lane == 0) excl = 1.0f;
            const float Tb   = Tc * excl;       // T_before (unmasked cumprod)
            const float proc = (Tb >= EARLY_STOP) ? 1.0f : 0.0f;
            const float contrib = Tb * ws * proc;
            ra += contrib * cr;
            ga += contrib * cg;
            ba += contrib * cb;
            da += Tb * proc * dep;
            wa += contrib;
            Tc *= __shfl(p, 63, 64);
        }
        // butterfly reduce the 5 sums
        #pragma unroll
        for (int off = 32; off > 0; off >>= 1) {
            ra += __shfl_down(ra, off, 64);
            ga += __shfl_down(ga, off, 64);
            ba += __shfl_down(ba, off, 64);
            da += __shfl_down(da, off, 64);
            wa += __shfl_down(wa, off, 64);
        }
        if (lane == 0) {
            out[b*3+0] = ra;
            out[b*3+1] = ga;
            out[b*3+2] = ba;
            out[B*3+b] = (total > 0) ? da : 100.0f;   // FAR_PLANE if no hit
            out[B*4+b] = wa;
        }
    }
}

extern "C" void kernel_launch(void* const* d_in, const int* in_sizes, int n_in,
                              void* d_out, int out_size, void* d_ws, size_t ws_size,
                              hipStream_t stream) {
    const float* positions = (const float*)d_in[0];
    const float* sizes     = (const float*)d_in[1];
    const float* densities = (const float*)d_in[2];
    const float* colors    = (const float*)d_in[3];
    const float* ray_o     = (const float*)d_in[4];
    const float* ray_d     = (const float*)d_in[5];
    const int N = in_sizes[1];          // 1024
    const int B = in_sizes[4] / 3;      // 2048

    voxel_raster<<<B, BLOCK, 0, stream>>>(
        positions, sizes, densities, colors, ray_o, ray_d, (float*)d_out, N, B);
}

// Round 4
// 70.652 us; speedup vs baseline: 1.1896x; 1.0349x over previous
//
#include <hip/hip_runtime.h>

// Block-per-ray, sort-free composite.
// Insight: T_before for hit l equals prod over {j : key_j < key_l} of
// (1-ws_j) — a predicate product, not a sequential cumprod. proc and all
// per-element contributions follow directly, and BG_COLOR=0 means T_final
// is never needed. So no argsort, no scatter, no scan.
// Phase 1: 4 consecutive voxels/thread, float4 loads, payload on hit,
// compact (key, ws, dep, rgb) into LDS via shared atomic.
// Phase 2 (wave 0): per-hit predicate product over broadcast LDS reads
// (m ~ 10 iterations), masked accumulate, butterfly reduce, write.
// 2 barriers, ~3.6 KB LDS, fast __expf in the divergent hit path.

#define BLOCK 256
#define CAP   128
#define EARLY_STOP 0.01f

__global__ __launch_bounds__(BLOCK) void voxel_raster(
    const float* __restrict__ positions, const float* __restrict__ sizes,
    const float* __restrict__ densities, const float* __restrict__ colors,
    const float* __restrict__ ray_o, const float* __restrict__ ray_d,
    float* __restrict__ out, int B)
{
    const int b   = blockIdx.x;
    const int tid = threadIdx.x;

    __shared__ int cnt;
    __shared__ unsigned long long key[CAP];
    __shared__ float h_ws[CAP], h_dep[CAP], h_r[CAP], h_g[CAP], h_b[CAP];

    if (tid == 0) cnt = 0;
    __syncthreads();

    const float ox = ray_o[b*3+0], oy = ray_o[b*3+1], oz = ray_o[b*3+2];
    const float dx = ray_d[b*3+0], dy = ray_d[b*3+1], dz = ray_d[b*3+2];
    const float ivx = 1.0f/dx, ivy = 1.0f/dy, ivz = 1.0f/dz;

    // degree-2 real SH basis at ray direction (block-uniform)
    float sh[9];
    sh[0]=1.0f; sh[1]=dy; sh[2]=dz; sh[3]=dx;
    sh[4]=dx*dy; sh[5]=dy*dz; sh[6]=3.0f*dz*dz-1.0f; sh[7]=dx*dz; sh[8]=dx*dx-dy*dy;

    // ---- phase 1: 4 consecutive voxels per thread, vectorized loads ----
    const float4 P0 = ((const float4*)positions)[tid*3+0];
    const float4 P1 = ((const float4*)positions)[tid*3+1];
    const float4 P2 = ((const float4*)positions)[tid*3+2];
    const float4 SZ = ((const float4*)sizes)[tid];

    const float pxa[4] = {P0.x, P0.w, P1.z, P2.y};
    const float pya[4] = {P0.y, P1.x, P1.w, P2.z};
    const float pza[4] = {P0.z, P1.y, P2.x, P2.w};
    const float hsa[4] = {SZ.x*0.5f, SZ.y*0.5f, SZ.z*0.5f, SZ.w*0.5f};

    #pragma unroll
    for (int k = 0; k < 4; ++k) {
        const int n = tid*4 + k;
        const float half = hsa[k];
        const float px = pxa[k], py = pya[k], pz = pza[k];

        float a0 = (px - half - ox) * ivx, a1 = (px + half - ox) * ivx;
        float tn = fminf(a0, a1), tf = fmaxf(a0, a1);
        a0 = (py - half - oy) * ivy; a1 = (py + half - oy) * ivy;
        tn = fmaxf(tn, fminf(a0, a1)); tf = fminf(tf, fmaxf(a0, a1));
        a0 = (pz - half - oz) * ivz; a1 = (pz + half - oz) * ivz;
        tn = fmaxf(tn, fminf(a0, a1)); tf = fminf(tf, fmaxf(a0, a1));

        if ((tf > tn) && (tf > 0.0f)) {
            // within-voxel alpha compositing (S=8, constant sigma)
            const float sigma = __expf(densities[n]);
            const float dt    = tf - tn;
            const float alpha = 1.0f - __expf(-sigma * dt * 0.125f);
            const float base  = 1.0f - alpha + 1e-8f;
            float pw = 1.0f, ws = 0.0f, dep = 0.0f;
            #pragma unroll
            for (int i = 0; i < 8; i++) {
                const float w  = alpha * pw;
                const float ts = tn + dt * ((float)i * (1.0f / 7.0f));
                ws  += w;
                dep += w * ts;
                pw  *= base;
            }
            // SH color + sigmoid
            float rgb[3];
            #pragma unroll
            for (int c3 = 0; c3 < 3; c3++) {
                float acc = 0.0f;
                #pragma unroll
                for (int c = 0; c < 9; c++)
                    acc += sh[c] * colors[n*27 + c3*9 + c];
                rgb[c3] = __fdividef(1.0f, 1.0f + __expf(-acc));
            }

            const int slot = atomicAdd(&cnt, 1);
            if (slot < CAP) {
                unsigned u = __float_as_uint(tn);
                u = (u & 0x80000000u) ? ~u : (u | 0x80000000u);
                key[slot]   = ((unsigned long long)u << 32) | (unsigned)n;
                h_ws[slot]  = ws;
                h_dep[slot] = dep;
                h_r[slot]   = rgb[0];
                h_g[slot]   = rgb[1];
                h_b[slot]   = rgb[2];
            }
        }
    }
    __syncthreads();

    const int total = cnt;
    const int m = (total < CAP) ? total : CAP;

    // ---- phase 2 (wave 0): sort-free predicate-product composite ----
    if (tid < 64) {
        float ra = 0.f, ga = 0.f, ba = 0.f, da = 0.f, wa = 0.f;
        for (int l = tid; l < m; l += 64) {
            const unsigned long long kl = key[l];
            float Tb = 1.0f;
            for (int j = 0; j < m; ++j) {            // broadcast LDS reads
                const unsigned long long kj = key[j];
                const float wj = h_ws[j];
                Tb *= (kj < kl) ? (1.0f - wj) : 1.0f;
            }
            if (Tb >= EARLY_STOP) {                  // proc mask
                const float ws = h_ws[l];
                const float c  = Tb * ws;
                ra += c * h_r[l];
                ga += c * h_g[l];
                ba += c * h_b[l];
                da += Tb * h_dep[l];
                wa += c;
            }
        }
        // butterfly reduce the 5 sums across the wave
        #pragma unroll
        for (int off = 32; off > 0; off >>= 1) {
            ra += __shfl_down(ra, off, 64);
            ga += __shfl_down(ga, off, 64);
            ba += __shfl_down(ba, off, 64);
            da += __shfl_down(da, off, 64);
            wa += __shfl_down(wa, off, 64);
        }
        if (tid == 0) {
            out[b*3+0] = ra;
            out[b*3+1] = ga;
            out[b*3+2] = ba;
            out[B*3+b] = (total > 0) ? da : 100.0f;   // FAR_PLANE if no hit
            out[B*4+b] = wa;
        }
    }
}

extern "C" void kernel_launch(void* const* d_in, const int* in_sizes, int n_in,
                              void* d_out, int out_size, void* d_ws, size_t ws_size,
                              hipStream_t stream) {
    const float* positions = (const float*)d_in[0];
    const float* sizes     = (const float*)d_in[1];
    const float* densities = (const float*)d_in[2];
    const float* colors    = (const float*)d_in[3];
    const float* ray_o     = (const float*)d_in[4];
    const float* ray_d     = (const float*)d_in[5];
    const int B = in_sizes[4] / 3;      // 2048 rays (N fixed at 1024)

    voxel_raster<<<B, BLOCK, 0, stream>>>(
        positions, sizes, densities, colors, ray_o, ray_d, (float*)d_out, B);
}